// Round 5
// baseline (28166.815 us; speedup 1.0000x reference)
//
#include <hip/hip_runtime.h>
#include <math.h>

// DenseLSTMForecast: B=256, T=1024, H=128, FUTURE=32.
// R5: weight-stationary pipeline. R1-R4 counters proved the streaming design's
// L2 miss floor is structural (FETCH bit-identical with/without phase-lock),
// and even perfect residency leaves a 768KB/step/CU L2-port floor (~6ms).
// New structure: 8 groups (blockIdx%8 -> same XCD), each owns 32 batch rows.
// Per group: 4 cell1-WGs + 8 cell2-WGs + 16 cell3-WGs + 1 head-WG, each with
// its weight slice PERMANENTLY in LDS. Stages exchange h-state (8KB fp16
// arrays, double-buffered by parity) via group-local global buffers using
// relaxed agent-scope atomics (coherent, no cache-walk fences), self-timed by
// monotonic per-stage flag counters. Pipeline depth 3 for t<1024; the 32
// autoregressive steps drain serially. Weights are fetched from HBM exactly
// once per launch.

#define TSEQ 1024
#define HH   128
#define TT   1056

// ---- ws dword offsets ----
#define PLANE_DW 196608            // 6 planes x 32768 dwords (fp16-packed, k-major)
#define SCAL     196608            // xw1,xw2,xw3,bs1,bs2,bs3 (512 floats each)
#define WLIN     199680            // 386 floats (W_lin row + b_lin), padded to 512
#define XT       200192            // x transposed: [1024 t][256 rows] fp32
#define GH1      462336            // h1: [2 parity][256 rows][128] fp16
#define GH2      495104
#define GH3      527872
#define GO       560640            // o feedback: [2 parity][256] fp32
#define FLAGS    561152            // 8 groups x 4 stages x 64-dword lines
#define WS_DWORDS 563200

#define GH1_64 (GH1/2)
#define GH2_64 (GH2/2)
#define GH3_64 (GH3/2)

#define HSTR 392                   // hIn LDS row stride in halves (384 + 8 pad)

typedef _Float16 h2t __attribute__((ext_vector_type(2)));
typedef _Float16 h8t __attribute__((ext_vector_type(8)));

__device__ __forceinline__ float sigmoidf_(float v) {
  return 1.0f / (1.0f + expf(-v));
}

__device__ __forceinline__ float dot8(uint4 wu, h8t h, float acc) {
  h2t w0 = __builtin_bit_cast(h2t, wu.x);
  h2t w1 = __builtin_bit_cast(h2t, wu.y);
  h2t w2 = __builtin_bit_cast(h2t, wu.z);
  h2t w3 = __builtin_bit_cast(h2t, wu.w);
  h2t p0 = {h[0], h[1]}, p1 = {h[2], h[3]}, p2 = {h[4], h[5]}, p3 = {h[6], h[7]};
  acc = __builtin_amdgcn_fdot2(w0, p0, acc, false);
  acc = __builtin_amdgcn_fdot2(w1, p1, acc, false);
  acc = __builtin_amdgcn_fdot2(w2, p2, acc, false);
  acc = __builtin_amdgcn_fdot2(w3, p3, acc, false);
  return acc;
}

__device__ __forceinline__ void wait_ge(unsigned* p, unsigned tgt) {
  while (__hip_atomic_load(p, __ATOMIC_ACQUIRE, __HIP_MEMORY_SCOPE_AGENT) < tgt)
    __builtin_amdgcn_s_sleep(1);
}

// ---------------------------------------------------------------------------
__global__ void prep_kernel(const float* __restrict__ x,
                            const float* __restrict__ Wih1, const float* __restrict__ Whh1,
                            const float* __restrict__ bih1, const float* __restrict__ bhh1,
                            const float* __restrict__ Wih2, const float* __restrict__ Whh2,
                            const float* __restrict__ bih2, const float* __restrict__ bhh2,
                            const float* __restrict__ Wih3, const float* __restrict__ Whh3,
                            const float* __restrict__ bih3, const float* __restrict__ bhh3,
                            const float* __restrict__ Wlin, const float* __restrict__ blin,
                            float* __restrict__ ws) {
  int idx = blockIdx.x * 256 + threadIdx.x;
  if (idx < PLANE_DW) {
    int p = idx >> 15;
    int rem = idx & 32767;
    int k8 = rem >> 11;
    int rem2 = rem & 2047;
    int g = rem2 >> 2;
    int q = rem2 & 3;
    int k = k8 * 8 + q * 2;
    float v0, v1;
    switch (p) {
      case 0:  v0 = Whh1[g * HH + k];        v1 = Whh1[g * HH + k + 1];     break;
      case 1:  v0 = Wih2[g * 129 + 1 + k];   v1 = Wih2[g * 129 + 2 + k];    break;
      case 2:  v0 = Whh2[g * HH + k];        v1 = Whh2[g * HH + k + 1];     break;
      case 3:  v0 = Wih3[g * 257 + 1 + k];   v1 = Wih3[g * 257 + 2 + k];    break;
      case 4:  v0 = Wih3[g * 257 + 129 + k]; v1 = Wih3[g * 257 + 130 + k];  break;
      default: v0 = Whh3[g * HH + k];        v1 = Whh3[g * HH + k + 1];     break;
    }
    unsigned short b0 = __builtin_bit_cast(unsigned short, (_Float16)v0);
    unsigned short b1 = __builtin_bit_cast(unsigned short, (_Float16)v1);
    ((unsigned int*)ws)[idx] = (unsigned int)b0 | ((unsigned int)b1 << 16);
  } else if (idx < WLIN) {
    int r = idx - SCAL;
    float v;
    if      (r < 512)  v = Wih1[r];
    else if (r < 1024) v = Wih2[(r - 512) * 129];
    else if (r < 1536) v = Wih3[(r - 1024) * 257];
    else if (r < 2048) v = bih1[r - 1536] + bhh1[r - 1536];
    else if (r < 2560) v = bih2[r - 2048] + bhh2[r - 2048];
    else               v = bih3[r - 2560] + bhh3[r - 2560];
    ws[idx] = v;
  } else if (idx < XT) {
    int j = idx - WLIN;
    ws[idx] = (j < 385) ? Wlin[j] : (j == 385 ? blin[0] : 0.0f);
  } else if (idx < GH1) {
    int j = idx - XT;
    int t = j >> 8, r = j & 255;
    ws[idx] = x[r * TSEQ + t];
  } else if (idx < WS_DWORDS) {
    ws[idx] = 0.0f;                // zero GH1/GH2/GH3/GO/FLAGS (ws is poisoned)
  }
}

// ---------------------------------------------------------------------------
// Cell stage. CI: 0/1/2. NU: units per WG. KP8: K/8. PB: source plane base.
// NSEG: h segments staged. Thread layout: col = tid % (4*NU), rb = tid / (4*NU),
// each thread accumulates A = NC/16 rows.
template <int CI, int NU, int KP8, int PB, int NSEG>
__device__ void cell_stage(float* wsm, char* SB, int g, int rank) {
  constexpr int NC = NU * 4;
  constexpr int A  = NC / 16;
  const int tid  = threadIdx.x;
  const int grow = g * 32;
  const int u0   = rank * NU;

  uint4*  wlds = (uint4*)SB;                       // KP8*NC uint4
  ushort* hInU = (ushort*)(SB + 32768);            // [32][HSTR] halves
  float*  gsF  = (float*)(SB + 32768);             // [32][NC] (aliases hInU)
  float*  xsh  = (float*)(SB + 57856);             // [32]
  ushort* hOutU= (ushort*)(SB + 57856 + 128);      // [32][NU]

  const uint4* ws4 = (const uint4*)wsm;
  unsigned long long* ws64 = (unsigned long long*)wsm;
  unsigned* flg = (unsigned*)(wsm + FLAGS) + (size_t)g * 256;
  unsigned* F0 = flg, *F1 = flg + 64, *F2 = flg + 128, *F3 = flg + 192;
  unsigned* Fself = flg + CI * 64;

  // load weight slice into LDS (once)
  for (int i = tid; i < KP8 * NC; i += 512) {
    int kk = i / NC, c = i - kk * NC;
    int colg = (c / NU) * HH + u0 + (c % NU);
    wlds[(size_t)kk * NC + c] =
        ws4[(size_t)(PB + (kk >> 4)) * 8192 + (size_t)(kk & 15) * 512 + colg];
  }
  const int col = tid % NC, rb = tid / NC;
  const int colg = (col / NU) * HH + u0 + (col % NU);
  const float xwv = wsm[SCAL + CI * 512 + colg];
  const float bsv = wsm[SCAL + 1536 + CI * 512 + colg];

  constexpr int PITER = (32 * NU + 511) / 512;
  float cst[PITER];
  #pragma unroll
  for (int p = 0; p < PITER; ++p) cst[p] = 0.0f;
  __syncthreads();

  for (int t = 0; t < TT; ++t) {
    // ---- waits ----
    if (tid == 0) {
      if (CI == 0) {
        if (t >= 1) wait_ge(F0, 4u * t);
        if (t >= 2) { wait_ge(F1, 8u * (t - 1)); wait_ge(F2, 16u * (t - 1)); wait_ge(F3, (unsigned)(t - 1)); }
      } else if (CI == 1) {
        wait_ge(F0, 4u * (t + 1));
        if (t >= 1) wait_ge(F1, 8u * t);
        if (t >= 2) { wait_ge(F2, 16u * (t - 1)); wait_ge(F3, (unsigned)(t - 1)); }
      } else {
        wait_ge(F0, 4u * (t + 1));
        wait_ge(F1, 8u * (t + 1));
        if (t >= 1) wait_ge(F2, 16u * t);
        if (t >= 2) wait_ge(F3, (unsigned)(t - 1));
      }
      if (t >= TSEQ) wait_ge(F3, (unsigned)t);     // o(t-1) feedback
    }
    __syncthreads();

    // ---- stage x and h into LDS ----
    if (tid < 32) {
      float xv;
      if (t < TSEQ) xv = wsm[XT + (size_t)t * 256 + grow + tid];
      else {
        unsigned u = __hip_atomic_load((unsigned*)wsm + GO + (size_t)((t - 1) & 1) * 256 + grow + tid,
                                       __ATOMIC_RELAXED, __HIP_MEMORY_SCOPE_AGENT);
        xv = __builtin_bit_cast(float, u);
      }
      xsh[tid] = xv;
    }
    {
      const int p0 = t & 1, p1 = (t + 1) & 1;
      size_t sb[3];
      if (CI == 0) { sb[0] = GH1_64 + (size_t)p1 * 8192; }
      else if (CI == 1) { sb[0] = GH1_64 + (size_t)p0 * 8192; sb[1] = GH2_64 + (size_t)p1 * 8192; }
      else { sb[0] = GH1_64 + (size_t)p0 * 8192; sb[1] = GH2_64 + (size_t)p0 * 8192; sb[2] = GH3_64 + (size_t)p1 * 8192; }
      #pragma unroll
      for (int s = 0; s < NSEG; ++s) {
        for (int i = tid; i < 1024; i += 512) {
          int row = i >> 5, j = i & 31;
          unsigned long long v = __hip_atomic_load(ws64 + sb[s] + (size_t)(grow + row) * 32 + j,
                                                   __ATOMIC_RELAXED, __HIP_MEMORY_SCOPE_AGENT);
          *(unsigned long long*)&hInU[row * HSTR + s * 128 + j * 4] = v;
        }
      }
    }
    __syncthreads();

    // ---- gate accumulation ----
    float acc[A];
    #pragma unroll
    for (int a = 0; a < A; ++a) acc[a] = fmaf(xwv, xsh[rb * A + a], bsv);
    #pragma unroll 4
    for (int k8 = 0; k8 < KP8; ++k8) {
      uint4 wv = wlds[(size_t)k8 * NC + col];
      #pragma unroll
      for (int a = 0; a < A; ++a) {
        h8t hv = *(const h8t*)&hInU[(rb * A + a) * HSTR + k8 * 8];
        acc[a] = dot8(wv, hv, acc[a]);
      }
    }
    __syncthreads();                 // hIn reads done before gs overwrite
    #pragma unroll
    for (int a = 0; a < A; ++a) gsF[(rb * A + a) * NC + col] = acc[a];
    __syncthreads();

    // ---- activation + c update ----
    #pragma unroll
    for (int p = 0; p < PITER; ++p) {
      int i = tid + p * 512;
      if (i < 32 * NU) {
        int row = i & 31, du = i >> 5;
        float gi = gsF[row * NC + 0 * NU + du];
        float gf = gsF[row * NC + 1 * NU + du];
        float gg = gsF[row * NC + 2 * NU + du];
        float go = gsF[row * NC + 3 * NU + du];
        float c = sigmoidf_(gf) * cst[p] + sigmoidf_(gi) * tanhf(gg);
        cst[p] = c;
        float h = sigmoidf_(go) * tanhf(c);
        hOutU[row * NU + du] = __builtin_bit_cast(unsigned short, (_Float16)h);
      }
    }
    __syncthreads();

    // ---- publish h slice ----
    {
      constexpr size_t GS = (CI == 0) ? GH1_64 : (CI == 1) ? GH2_64 : GH3_64;
      for (int i = tid; i < 8 * NU; i += 512) {      // 32*NU/4 u64 words
        int row = i / (NU / 4), jj = i % (NU / 4);
        unsigned long long v = *(unsigned long long*)&hOutU[row * NU + jj * 4];
        __hip_atomic_store(ws64 + GS + (size_t)(t & 1) * 8192 + (size_t)(grow + row) * 32 + (u0 >> 2) + jj,
                           v, __ATOMIC_RELAXED, __HIP_MEMORY_SCOPE_AGENT);
      }
    }
    __syncthreads();                 // barrier drains vmcnt -> stores coherent
    if (tid == 0)
      __hip_atomic_fetch_add(Fself, 1u, __ATOMIC_RELAXED, __HIP_MEMORY_SCOPE_AGENT);
  }
}

// ---------------------------------------------------------------------------
__device__ void head_stage(float* wsm, char* SB, int g, float* out) {
  const int tid  = threadIdx.x;
  const int grow = g * 32;

  float*  wlF  = (float*)SB;                        // 386
  float*  psum = (float*)(SB + 2048);               // [32][16]
  float*  obuf = (float*)(SB + 4096);               // [32][32]
  float*  xv   = (float*)(SB + 8192);               // [32]
  ushort* hInU = (ushort*)(SB + 32768);             // [32][HSTR]

  unsigned long long* ws64 = (unsigned long long*)wsm;
  unsigned* flg = (unsigned*)(wsm + FLAGS) + (size_t)g * 256;
  unsigned* F0 = flg, *F1 = flg + 64, *F2 = flg + 128, *F3 = flg + 192;

  for (int i = tid; i < 386; i += 512) wlF[i] = wsm[WLIN + i];
  if (tid < 32) xv[tid] = wsm[XT + grow + tid];
  __syncthreads();

  for (int t = 0; t < TT; ++t) {
    if (tid == 0) {
      wait_ge(F0, 4u * (t + 1));
      wait_ge(F1, 8u * (t + 1));
      wait_ge(F2, 16u * (t + 1));
    }
    __syncthreads();

    {
      const int p0 = t & 1;
      size_t sb[3] = { GH1_64 + (size_t)p0 * 8192, GH2_64 + (size_t)p0 * 8192, GH3_64 + (size_t)p0 * 8192 };
      #pragma unroll
      for (int s = 0; s < 3; ++s) {
        for (int i = tid; i < 1024; i += 512) {
          int row = i >> 5, j = i & 31;
          unsigned long long v = __hip_atomic_load(ws64 + sb[s] + (size_t)(grow + row) * 32 + j,
                                                   __ATOMIC_RELAXED, __HIP_MEMORY_SCOPE_AGENT);
          *(unsigned long long*)&hInU[row * HSTR + s * 128 + j * 4] = v;
        }
      }
    }
    __syncthreads();

    // partial dot: thread = (row, part), 24 terms each
    {
      int row = tid >> 4, part = tid & 15;
      int j0 = part * 24;
      float s = 0.f;
      #pragma unroll 8
      for (int m = 0; m < 24; ++m) {
        _Float16 hv = __builtin_bit_cast(_Float16, hInU[row * HSTR + j0 + m]);
        s = fmaf(wlF[1 + j0 + m], (float)hv, s);
      }
      psum[tid] = s;
    }
    __syncthreads();

    if (tid < 32) {
      int row = tid;
      float o = wlF[385] + wlF[0] * xv[row];
      #pragma unroll
      for (int m = 0; m < 16; ++m) o += psum[row * 16 + m];
      obuf[row * 32 + (t & 31)] = o;
      __hip_atomic_store((unsigned*)wsm + GO + (size_t)(t & 1) * 256 + grow + row,
                         __builtin_bit_cast(unsigned, o),
                         __ATOMIC_RELAXED, __HIP_MEMORY_SCOPE_AGENT);
      xv[row] = (t + 1 < TSEQ) ? wsm[XT + (size_t)(t + 1) * 256 + grow + row] : o;
    }
    __syncthreads();
    if (tid == 0)
      __hip_atomic_fetch_add(F3, 1u, __ATOMIC_RELAXED, __HIP_MEMORY_SCOPE_AGENT);

    if ((t & 31) == 31) {
      int tbase = t - 31;
      for (int i = tid; i < 1024; i += 512) {
        int row = i >> 5, m = i & 31;
        out[(size_t)(grow + row) * TT + tbase + m] = obuf[row * 32 + m];
      }
    }
  }
}

// ---------------------------------------------------------------------------
__global__ __launch_bounds__(512, 1)
void lstm_kernel(float* __restrict__ wsm, float* __restrict__ out) {
  __shared__ __align__(16) char SB[60160];
  const int g = blockIdx.x & 7;
  const int rank = blockIdx.x >> 3;
  if (rank < 4)        cell_stage<0, 32, 16, 0, 1>(wsm, SB, g, rank);
  else if (rank < 12)  cell_stage<1, 16, 32, 1, 2>(wsm, SB, g, rank - 4);
  else if (rank < 28)  cell_stage<2,  8, 48, 3, 3>(wsm, SB, g, rank - 12);
  else if (rank == 28) head_stage(wsm, SB, g, out);
  // ranks 29..31: idle
}

// ---------------------------------------------------------------------------
extern "C" void kernel_launch(void* const* d_in, const int* in_sizes, int n_in,
                              void* d_out, int out_size, void* d_ws, size_t ws_size,
                              hipStream_t stream) {
  const float* x    = (const float*)d_in[0];
  const float* Wih1 = (const float*)d_in[1];
  const float* Whh1 = (const float*)d_in[2];
  const float* bih1 = (const float*)d_in[3];
  const float* bhh1 = (const float*)d_in[4];
  const float* Wih2 = (const float*)d_in[5];
  const float* Whh2 = (const float*)d_in[6];
  const float* bih2 = (const float*)d_in[7];
  const float* bhh2 = (const float*)d_in[8];
  const float* Wih3 = (const float*)d_in[9];
  const float* Whh3 = (const float*)d_in[10];
  const float* bih3 = (const float*)d_in[11];
  const float* bhh3 = (const float*)d_in[12];
  const float* Wlin = (const float*)d_in[13];
  const float* blin = (const float*)d_in[14];
  float* ws  = (float*)d_ws;
  float* out = (float*)d_out;

  prep_kernel<<<(WS_DWORDS + 255) / 256, 256, 0, stream>>>(
      x, Wih1, Whh1, bih1, bhh1, Wih2, Whh2, bih2, bhh2,
      Wih3, Whh3, bih3, bhh3, Wlin, blin, ws);
  lstm_kernel<<<256, 512, 0, stream>>>(ws, out);
}

// Round 7
// 8099.821 us; speedup vs baseline: 3.4775x; 3.4775x over previous
//
#include <hip/hip_runtime.h>
#include <math.h>

// DenseLSTMForecast: B=256, T=1024, H=128, FUTURE=32.
// R7: FULL-FP32 recurrence-decoupled pipeline.
// R6 post-mortem: fp16 h-state noise (2^-11) chaotically amplified through the
// 1056-step recurrence + 32 autoregressive steps gives absmax draws of
// {9.77e-4, 5.37e-3} vs threshold 5.35e-3 — a lottery. fp32 everywhere puts
// noise seeds at 2^-24 (R1 measured 4.88e-4, 11x margin).
// Structure: each cell's RECURRENT core is only Whh*h_self (K=128 = 128 fp32
// VGPRs/thread). Cross-layer terms are feed-forward -> computed ahead by
// helper WGs using pipeline slack. 32 row-groups (8 rows each) x 7 stages:
//   s0 c1-core   : g1 = xw1*x+b1 + Whh1*h1           -> RH1 ring
//   s1 c2-helper : p2 = xw2*x+b2 + Wih2[:,1:]*h1(t)  -> RP2 ring
//   s2 c2-core   : g2 = p2 + Whh2*h2                 -> RH2 ring
//   s3 c3-helperA: pA = xw3*x+b3 + Wih3[:,1:129]*h1  -> RP3A ring
//   s4 c3-helperB: pB = Wih3[:,129:257]*h2           -> RP3B ring
//   s5 c3-core   : g3 = pA+pB + Whh3*h3              -> RH3 ring
//   s6 head      : o = Wlin.[x,h1,h2,h3]+b           -> RO ring + out
// 224 WGs x 512 thr (all co-resident); group g's stages share XCD (bid%8).
// Sync: monotonic per-stage flags, tid0-cached (one poll grants many steps);
// payload moves via relaxed agent-scope atomics (coherence point; no fences).
// Anti-deps gated on the group's head flag (last transitive consumer).
// t>=1024: o->x feedback serializes the chain automatically (32 steps).

#define TSEQ 1024
#define HH   128
#define TT   1056

// ---- ws dword offsets ----
#define PLANES   0                 // 6 planes x [128 k][512 g] fp32
#define SCAL     393216            // xw1,xw2,xw3,bs1,bs2,bs3 (512 each)
#define WLIN     396288            // Wlin[0..384], [385]=b_lin, pad 512
#define XT       396800            // x transposed [1024][256]
#define RH1      658944            // h rings: [16][256][128] fp32
#define RH2      1183232
#define RH3      1707520
#define RO       2231808           // o ring [16][256] fp32
#define RP2      2235904           // partial rings: [8][256][512] fp32
#define RP3A     3284480
#define RP3B     4333056
#define FLAGS    5381632           // 224 x 32-dword lines
#define PREP_TOT 666112            // 658944 + 7168 (flags zeroing)

#define RH1_64 (RH1/2)
#define RH2_64 (RH2/2)
#define RH3_64 (RH3/2)

typedef unsigned long long u64;

__device__ __forceinline__ float sigmoidf_(float v) {
  return 1.0f / (1.0f + expf(-v));
}

__device__ __forceinline__ void wait_c(unsigned* p, unsigned tgt, unsigned& cached) {
  if (cached >= tgt) return;
  unsigned v = __hip_atomic_load(p, __ATOMIC_ACQUIRE, __HIP_MEMORY_SCOPE_AGENT);
  while (v < tgt) {
    __builtin_amdgcn_s_sleep(1);
    v = __hip_atomic_load(p, __ATOMIC_ACQUIRE, __HIP_MEMORY_SCOPE_AGENT);
  }
  cached = v;
}

// ---------------------------------------------------------------------------
__global__ void prep_kernel(const float* __restrict__ x,
                            const float* __restrict__ Wih1, const float* __restrict__ Whh1,
                            const float* __restrict__ bih1, const float* __restrict__ bhh1,
                            const float* __restrict__ Wih2, const float* __restrict__ Whh2,
                            const float* __restrict__ bih2, const float* __restrict__ bhh2,
                            const float* __restrict__ Wih3, const float* __restrict__ Whh3,
                            const float* __restrict__ bih3, const float* __restrict__ bhh3,
                            const float* __restrict__ Wlin, const float* __restrict__ blin,
                            float* __restrict__ ws) {
  int idx = blockIdx.x * 256 + threadIdx.x;
  if (idx < SCAL) {
    int p = idx >> 16;            // plane
    int rem = idx & 65535;
    int k = rem >> 9, g = rem & 511;
    float v;
    switch (p) {
      case 0:  v = Whh1[g * HH + k];         break;
      case 1:  v = Wih2[g * 129 + 1 + k];    break;
      case 2:  v = Whh2[g * HH + k];         break;
      case 3:  v = Wih3[g * 257 + 1 + k];    break;
      case 4:  v = Wih3[g * 257 + 129 + k];  break;
      default: v = Whh3[g * HH + k];         break;
    }
    ws[idx] = v;
  } else if (idx < WLIN) {
    int r = idx - SCAL;
    float v;
    if      (r < 512)  v = Wih1[r];
    else if (r < 1024) v = Wih2[(r - 512) * 129];
    else if (r < 1536) v = Wih3[(r - 1024) * 257];
    else if (r < 2048) v = bih1[r - 1536] + bhh1[r - 1536];
    else if (r < 2560) v = bih2[r - 2048] + bhh2[r - 2048];
    else               v = bih3[r - 2560] + bhh3[r - 2560];
    ws[idx] = v;
  } else if (idx < XT) {
    int j = idx - WLIN;
    ws[idx] = (j < 385) ? Wlin[j] : (j == 385 ? blin[0] : 0.0f);
  } else if (idx < RH1) {
    int j = idx - XT;
    int t = j >> 8, r = j & 255;
    ws[idx] = x[r * TSEQ + t];
  } else if (idx < PREP_TOT) {
    ws[FLAGS + (idx - RH1)] = 0.0f;   // zero flag lines (ws is 0xAA-poisoned)
  }
}

// ---------------------------------------------------------------------------
// Shared k-loop: acc[a] += sum_k w[k] * hbuf[a][k]  (hbuf LDS, broadcast reads)
__device__ __forceinline__ void dot128(const float* __restrict__ w,
                                       const float* __restrict__ hbuf,
                                       float acc[8]) {
  #pragma unroll
  for (int k4 = 0; k4 < 32; ++k4) {
    const float w0 = w[4 * k4], w1 = w[4 * k4 + 1];
    const float w2 = w[4 * k4 + 2], w3 = w[4 * k4 + 3];
    #pragma unroll
    for (int a = 0; a < 8; ++a) {
      const float4 h4 = *(const float4*)&hbuf[a * HH + k4 * 4];
      acc[a] = fmaf(w0, h4.x, fmaf(w1, h4.y, fmaf(w2, h4.z, fmaf(w3, h4.w, acc[a]))));
    }
  }
}

// ---------------------------------------------------------------------------
// Core stage: gates = [partials or x-term] + Whh*h_own; activation; publish h.
// SSELF/SWA/SWB: flag stage ids. NP: #partial rings. XF: x-fold (c1 only).
template <int SSELF, int SWA, int SWB, int NP, int XF, int PB, int PR1, int PR2, int DRH64>
__device__ void core_stage(float* __restrict__ wsm, char* SB, int g) {
  const int tid = threadIdx.x;
  const int r0 = g * 8;
  float* gs   = (float*)SB;                 // [8][512]
  float* hown = (float*)(SB + 16384);       // [8][128]
  float* xs   = (float*)(SB + 20480);       // [8]

  u64* ws64 = (u64*)wsm;
  unsigned* flagb = (unsigned*)wsm + FLAGS;
  unsigned* Fself = flagb + (size_t)(SSELF * 32 + g) * 32;
  unsigned* Fh    = flagb + (size_t)(6 * 32 + g) * 32;
  unsigned ca = 0, cb = 0, ch = 0;

  float w[128];
  #pragma unroll
  for (int k = 0; k < 128; ++k)
    w[k] = wsm[(size_t)PB * 65536 + (size_t)k * 512 + tid];
  const float xwv = XF ? wsm[SCAL + tid] : 0.f;
  const float bsv = XF ? wsm[SCAL + 1536 + tid] : 0.f;

  for (int i = tid; i < 1024; i += 512) hown[i] = 0.f;
  float cst0 = 0.f, cst1 = 0.f;
  __syncthreads();

  for (int t = 0; t < TT; ++t) {
    if (tid == 0) {
      if constexpr (SWA >= 0)
        wait_c(flagb + (size_t)(SWA * 32 + g) * 32, (unsigned)(t + 1), ca);
      if constexpr (SWB >= 0)
        wait_c(flagb + (size_t)(SWB * 32 + g) * 32, (unsigned)(t + 1), cb);
      unsigned ht = (t >= 15) ? (unsigned)(t - 14) : 0u;
      if (XF && t >= TSEQ && (unsigned)t > ht) ht = (unsigned)t;
      if (ht) wait_c(Fh, ht, ch);
    }
    __syncthreads();
    const int slot = t & 15;

    if (XF) {
      if (tid < 8) {
        float xv;
        if (t < TSEQ) {
          xv = wsm[XT + (size_t)t * 256 + r0 + tid];
        } else {
          unsigned u = __hip_atomic_load(
              (unsigned*)wsm + RO + (size_t)((t - 1) & 15) * 256 + r0 + tid,
              __ATOMIC_RELAXED, __HIP_MEMORY_SCOPE_AGENT);
          xv = __builtin_bit_cast(float, u);
        }
        xs[tid] = xv;
      }
      __syncthreads();
    }

    float acc[8];
    if constexpr (NP == 0) {
      #pragma unroll
      for (int a = 0; a < 8; ++a) acc[a] = fmaf(xwv, xs[a], bsv);
    } else {
      #pragma unroll
      for (int a = 0; a < 8; ++a) {
        unsigned u = __hip_atomic_load(
            (unsigned*)wsm + PR1 + (size_t)(t & 7) * 131072 + (size_t)(r0 + a) * 512 + tid,
            __ATOMIC_RELAXED, __HIP_MEMORY_SCOPE_AGENT);
        acc[a] = __builtin_bit_cast(float, u);
      }
      if constexpr (NP == 2) {
        #pragma unroll
        for (int a = 0; a < 8; ++a) {
          unsigned u = __hip_atomic_load(
              (unsigned*)wsm + PR2 + (size_t)(t & 7) * 131072 + (size_t)(r0 + a) * 512 + tid,
              __ATOMIC_RELAXED, __HIP_MEMORY_SCOPE_AGENT);
          acc[a] += __builtin_bit_cast(float, u);
        }
      }
    }

    dot128(w, hown, acc);

    #pragma unroll
    for (int a = 0; a < 8; ++a) gs[a * 512 + tid] = acc[a];
    __syncthreads();

    // activation: 1024 units / 512 thr = 2 each (rows 0-3 then 4-7)
    {
      const int row0 = tid >> 7, u0 = tid & 127;
      const float gi = gs[row0 * 512 + u0];
      const float gf = gs[row0 * 512 + 128 + u0];
      const float gg = gs[row0 * 512 + 256 + u0];
      const float go = gs[row0 * 512 + 384 + u0];
      const float c0 = sigmoidf_(gf) * cst0 + sigmoidf_(gi) * tanhf(gg);
      cst0 = c0;
      hown[row0 * HH + u0] = sigmoidf_(go) * tanhf(c0);

      const int i1 = tid + 512;
      const int row1 = i1 >> 7, u1 = i1 & 127;
      const float hi = gs[row1 * 512 + u1];
      const float hf = gs[row1 * 512 + 128 + u1];
      const float hg = gs[row1 * 512 + 256 + u1];
      const float ho = gs[row1 * 512 + 384 + u1];
      const float c1v = sigmoidf_(hf) * cst1 + sigmoidf_(hi) * tanhf(hg);
      cst1 = c1v;
      hown[row1 * HH + u1] = sigmoidf_(ho) * tanhf(c1v);
    }
    __syncthreads();

    // publish h(t): 512 u64 pairs
    {
      const int a = tid >> 6, up = tid & 63;
      u64 v = *(const u64*)&hown[a * HH + up * 2];
      __hip_atomic_store(
          ws64 + DRH64 + (size_t)slot * 16384 + (size_t)(r0 + a) * 64 + up, v,
          __ATOMIC_RELAXED, __HIP_MEMORY_SCOPE_AGENT);
    }
    __syncthreads();                 // vmcnt drained at barrier
    if (tid == 0)
      __hip_atomic_fetch_add(Fself, 1u, __ATOMIC_RELAXED, __HIP_MEMORY_SCOPE_AGENT);
  }
}

// ---------------------------------------------------------------------------
// Helper stage: partial = [x-term+bias if XF] + Wpart * h_src(t); publish.
template <int SSELF, int SW, int XF, int PB, int SI, int SRH64, int DRP>
__device__ void helper_stage(float* __restrict__ wsm, char* SB, int g) {
  const int tid = threadIdx.x;
  const int r0 = g * 8;
  float* hin = (float*)SB;                  // [8][128]
  float* xs  = (float*)(SB + 4096);         // [8]

  u64* ws64 = (u64*)wsm;
  unsigned* flagb = (unsigned*)wsm + FLAGS;
  unsigned* Fself = flagb + (size_t)(SSELF * 32 + g) * 32;
  unsigned* Fw    = flagb + (size_t)(SW * 32 + g) * 32;
  unsigned* Fh    = flagb + (size_t)(6 * 32 + g) * 32;
  unsigned cw = 0, ch = 0;

  float w[128];
  #pragma unroll
  for (int k = 0; k < 128; ++k)
    w[k] = wsm[(size_t)PB * 65536 + (size_t)k * 512 + tid];
  const float xwv = XF ? wsm[SCAL + SI * 512 + tid] : 0.f;
  const float bsv = XF ? wsm[SCAL + 1536 + SI * 512 + tid] : 0.f;
  __syncthreads();

  for (int t = 0; t < TT; ++t) {
    if (tid == 0) {
      wait_c(Fw, (unsigned)(t + 1), cw);
      unsigned ht = (t >= 7) ? (unsigned)(t - 6) : 0u;
      if (XF && t >= TSEQ && (unsigned)t > ht) ht = (unsigned)t;
      if (ht) wait_c(Fh, ht, ch);
    }
    __syncthreads();
    const int slot = t & 15;

    if (XF) {
      if (tid < 8) {
        float xv;
        if (t < TSEQ) {
          xv = wsm[XT + (size_t)t * 256 + r0 + tid];
        } else {
          unsigned u = __hip_atomic_load(
              (unsigned*)wsm + RO + (size_t)((t - 1) & 15) * 256 + r0 + tid,
              __ATOMIC_RELAXED, __HIP_MEMORY_SCOPE_AGENT);
          xv = __builtin_bit_cast(float, u);
        }
        xs[tid] = xv;
      }
    }
    // stage h_src(t)
    {
      const int a = tid >> 6, up = tid & 63;
      u64 v = __hip_atomic_load(
          ws64 + SRH64 + (size_t)slot * 16384 + (size_t)(r0 + a) * 64 + up,
          __ATOMIC_RELAXED, __HIP_MEMORY_SCOPE_AGENT);
      *(u64*)&hin[a * HH + up * 2] = v;
    }
    __syncthreads();

    float acc[8];
    #pragma unroll
    for (int a = 0; a < 8; ++a) acc[a] = XF ? fmaf(xwv, xs[a], bsv) : 0.f;

    dot128(w, hin, acc);

    #pragma unroll
    for (int a = 0; a < 8; ++a)
      __hip_atomic_store(
          (unsigned*)wsm + DRP + (size_t)(t & 7) * 131072 + (size_t)(r0 + a) * 512 + tid,
          __builtin_bit_cast(unsigned, acc[a]),
          __ATOMIC_RELAXED, __HIP_MEMORY_SCOPE_AGENT);
    __syncthreads();                 // vmcnt drained
    if (tid == 0)
      __hip_atomic_fetch_add(Fself, 1u, __ATOMIC_RELAXED, __HIP_MEMORY_SCOPE_AGENT);
  }
}

// ---------------------------------------------------------------------------
__device__ void head_stage(float* __restrict__ wsm, char* SB, int g,
                           float* __restrict__ out) {
  const int tid = threadIdx.x;
  const int r0 = g * 8;
  float* wl   = (float*)SB;                 // [512]
  float* hin  = (float*)(SB + 2048);        // [3][8][128]
  float* obuf = (float*)(SB + 14336);       // [8][32]
  float* xv   = (float*)(SB + 15360);       // [8]

  u64* ws64 = (u64*)wsm;
  unsigned* flagb = (unsigned*)wsm + FLAGS;
  unsigned* Fself = flagb + (size_t)(6 * 32 + g) * 32;
  unsigned* Fc3   = flagb + (size_t)(5 * 32 + g) * 32;
  unsigned c3c = 0;

  wl[tid] = wsm[WLIN + tid];
  if (tid < 8) xv[tid] = wsm[XT + r0 + tid];
  __syncthreads();

  const int row = tid >> 6, lane = tid & 63;

  for (int t = 0; t < TT; ++t) {
    if (tid == 0) wait_c(Fc3, (unsigned)(t + 1), c3c);
    __syncthreads();
    const int slot = t & 15;

    for (int i = tid; i < 1536; i += 512) {
      const int s = i >> 9, rem = i & 511;
      const int a = rem >> 6, up = rem & 63;
      const size_t base = (s == 0) ? (size_t)RH1_64 : (s == 1) ? (size_t)RH2_64 : (size_t)RH3_64;
      u64 v = __hip_atomic_load(
          ws64 + base + (size_t)slot * 16384 + (size_t)(r0 + a) * 64 + up,
          __ATOMIC_RELAXED, __HIP_MEMORY_SCOPE_AGENT);
      *(u64*)&hin[(s * 8 + a) * HH + up * 2] = v;
    }
    __syncthreads();

    float s = 0.f;
    #pragma unroll
    for (int q = 0; q < 6; ++q) {
      const int j = lane + 64 * q;          // 0..383
      const int si = j >> 7, u = j & 127;
      s = fmaf(wl[1 + j], hin[(si * 8 + row) * HH + u], s);
    }
    #pragma unroll
    for (int off = 32; off > 0; off >>= 1) s += __shfl_down(s, off, 64);
    if (lane == 0) {
      const float o = s + fmaf(wl[0], xv[row], wl[385]);
      obuf[row * 32 + (t & 31)] = o;
      __hip_atomic_store((unsigned*)wsm + RO + (size_t)slot * 256 + r0 + row,
                         __builtin_bit_cast(unsigned, o),
                         __ATOMIC_RELAXED, __HIP_MEMORY_SCOPE_AGENT);
      xv[row] = (t + 1 < TSEQ) ? wsm[XT + (size_t)(t + 1) * 256 + r0 + row] : o;
    }
    __syncthreads();                 // drain o-store + obuf
    if (tid == 0)
      __hip_atomic_fetch_add(Fself, 1u, __ATOMIC_RELAXED, __HIP_MEMORY_SCOPE_AGENT);

    if ((t & 31) == 31) {
      const int tb = t - 31;
      if (tid < 256) {
        const int a = tid >> 5, m = tid & 31;
        out[(size_t)(r0 + a) * TT + tb + m] = obuf[a * 32 + m];
      }
    }
  }
}

// ---------------------------------------------------------------------------
__global__ __launch_bounds__(512, 2)
void lstm_kernel(float* __restrict__ wsm, float* __restrict__ out) {
  __shared__ __align__(16) char SB[20992];
  const int s = blockIdx.x >> 5, g = blockIdx.x & 31;
  switch (s) {
    case 0: core_stage<0, -1, -1, 0, 1, 0, 0, 0, RH1_64>(wsm, SB, g); break;
    case 1: helper_stage<1, 0, 1, 1, 1, RH1_64, RP2>(wsm, SB, g); break;
    case 2: core_stage<2, 1, -1, 1, 0, 2, RP2, 0, RH2_64>(wsm, SB, g); break;
    case 3: helper_stage<3, 0, 1, 3, 2, RH1_64, RP3A>(wsm, SB, g); break;
    case 4: helper_stage<4, 2, 0, 4, 0, RH2_64, RP3B>(wsm, SB, g); break;
    case 5: core_stage<5, 3, 4, 2, 0, 5, RP3A, RP3B, RH3_64>(wsm, SB, g); break;
    default: head_stage(wsm, SB, g, out); break;
  }
}

// ---------------------------------------------------------------------------
extern "C" void kernel_launch(void* const* d_in, const int* in_sizes, int n_in,
                              void* d_out, int out_size, void* d_ws, size_t ws_size,
                              hipStream_t stream) {
  const float* x    = (const float*)d_in[0];
  const float* Wih1 = (const float*)d_in[1];
  const float* Whh1 = (const float*)d_in[2];
  const float* bih1 = (const float*)d_in[3];
  const float* bhh1 = (const float*)d_in[4];
  const float* Wih2 = (const float*)d_in[5];
  const float* Whh2 = (const float*)d_in[6];
  const float* bih2 = (const float*)d_in[7];
  const float* bhh2 = (const float*)d_in[8];
  const float* Wih3 = (const float*)d_in[9];
  const float* Whh3 = (const float*)d_in[10];
  const float* bih3 = (const float*)d_in[11];
  const float* bhh3 = (const float*)d_in[12];
  const float* Wlin = (const float*)d_in[13];
  const float* blin = (const float*)d_in[14];
  float* ws  = (float*)d_ws;
  float* out = (float*)d_out;

  prep_kernel<<<PREP_TOT / 256, 256, 0, stream>>>(
      x, Wih1, Whh1, bih1, bhh1, Wih2, Whh2, bih2, bhh2,
      Wih3, Whh3, bih3, bhh3, Wlin, blin, ws);
  lstm_kernel<<<224, 512, 0, stream>>>(ws, out);
}